// Round 1
// baseline (552.298 us; speedup 1.0000x reference)
//
#include <hip/hip_runtime.h>

#define HID 1024
#define SEQ 2048
#define NB  16
#define MTOT (NB * SEQ)   // 32768 rows

typedef __attribute__((ext_vector_type(8))) short bf16x8;
typedef __attribute__((ext_vector_type(4))) float f32x4;

static __device__ __forceinline__ short f2bf(float f) {
    union { float f; unsigned u; } v; v.f = f;
    unsigned u = v.u + 0x7fffu + ((v.u >> 16) & 1u);   // round-to-nearest-even
    return (short)(u >> 16);
}

// ---- prep 1: W1 bottom half -> transposed bf16 w1t[n][k] = bf16(W1[H+k][n]) ----
__global__ __launch_bounds__(256) void prep_w1t(const float* __restrict__ W1,
                                                short* __restrict__ w1t) {
    __shared__ float t[32][33];
    const int k0 = blockIdx.x * 32;
    const int n0 = blockIdx.y * 32;
    const int tx = threadIdx.x & 31;
    const int ty = threadIdx.x >> 5;       // 0..7
#pragma unroll
    for (int i = 0; i < 32; i += 8)
        t[ty + i][tx] = W1[(size_t)(HID + k0 + ty + i) * HID + n0 + tx];
    __syncthreads();
#pragma unroll
    for (int i = 0; i < 32; i += 8)
        w1t[(size_t)(n0 + ty + i) * HID + k0 + tx] = f2bf(t[tx][ty + i]);
}

// ---- prep 2: qproj[b][n] = b1[n] + sum_f q[b][f] * W1[f][n]  (fp32, split-f atomics) ----
__global__ __launch_bounds__(256) void prep_qproj(const float* __restrict__ queries,
                                                  const float* __restrict__ W1,
                                                  const float* __restrict__ b1,
                                                  float* __restrict__ qproj) {
    const int n  = blockIdx.x * 256 + threadIdx.x;
    const int f0 = blockIdx.y * 256;
    const int b  = blockIdx.z;
    float acc = (blockIdx.y == 0) ? b1[n] : 0.0f;
    const float* q = queries + b * HID + f0;
    const float* w = W1 + (size_t)f0 * HID + n;
#pragma unroll 4
    for (int f = 0; f < 256; ++f)
        acc += q[f] * w[(size_t)f * HID];
    atomicAdd(&qproj[b * HID + n], acc);
}

// ---- main: fused score GEMM.  scores[m] += sum_n relu(keys[m]·W1bot[:,n] + qproj[b][n]) * W2[n]
// 64x64 tile, BK=32 (one 16x16x32 MFMA K-step), 4 waves stacked over M.
__global__ __launch_bounds__(256) void score_gemm(const float* __restrict__ keys,
                                                  const short* __restrict__ w1t,
                                                  const float* __restrict__ qproj,
                                                  const float* __restrict__ W2,
                                                  float* __restrict__ scores) {
    __shared__ short As[64][40];   // [m][k] bf16, +8 pad
    __shared__ short Bs[64][40];   // [n][k] bf16, +8 pad

    const int tid  = threadIdx.x;
    const int lane = tid & 63;
    const int wave = tid >> 6;
    const int n0 = blockIdx.x * 64;
    const int m0 = blockIdx.y * 64;
    const int batch = m0 >> 11;            // 2048 rows per batch, tiles never straddle

    const int arow = tid >> 3;             // 0..31
    const int akk  = (tid & 7) * 4;        // 0..28
    const int bn   = tid >> 2;             // 0..63
    const int bkk  = (tid & 3) * 8;        // 0..24

    const int q = lane >> 4;               // quad 0..3
    const int c = lane & 15;

    f32x4 acc[4] = {};                     // 4 N-frags of 16 cols; 16 rows per wave

    for (int k0 = 0; k0 < HID; k0 += 32) {
        // stage A: keys fp32 -> bf16, 64x32
#pragma unroll
        for (int it = 0; it < 2; ++it) {
            const float4 v = *(const float4*)(keys + (size_t)(m0 + arow + it * 32) * HID + k0 + akk);
            unsigned lo = (unsigned short)f2bf(v.x) | ((unsigned)(unsigned short)f2bf(v.y) << 16);
            unsigned hi = (unsigned short)f2bf(v.z) | ((unsigned)(unsigned short)f2bf(v.w) << 16);
            int2 pk; pk.x = (int)lo; pk.y = (int)hi;
            *(int2*)&As[arow + it * 32][akk] = pk;
        }
        // stage B: w1t bf16, 64 n-rows x 32 k
        *(int4*)&Bs[bn][bkk] = *(const int4*)(w1t + (size_t)(n0 + bn) * HID + k0 + bkk);
        __syncthreads();

        const bf16x8 a = *(const bf16x8*)&As[wave * 16 + c][q * 8];
#pragma unroll
        for (int f = 0; f < 4; ++f) {
            const bf16x8 bfr = *(const bf16x8*)&Bs[f * 16 + c][q * 8];
            acc[f] = __builtin_amdgcn_mfma_f32_16x16x32_bf16(a, bfr, acc[f], 0, 0, 0);
        }
        __syncthreads();
    }

    // epilogue: relu(acc + qproj[n]) * W2[n], reduce over n
    const float* qp = qproj + batch * HID + n0;
    float psum[4] = {0.f, 0.f, 0.f, 0.f};
#pragma unroll
    for (int f = 0; f < 4; ++f) {
        const int nl = f * 16 + c;
        const float qv = qp[nl];
        const float wv = W2[n0 + nl];
#pragma unroll
        for (int r = 0; r < 4; ++r) {
            float val = acc[f][r] + qv;
            val = fmaxf(val, 0.0f);
            psum[r] += val * wv;
        }
    }
#pragma unroll
    for (int m = 1; m < 16; m <<= 1) {
#pragma unroll
        for (int r = 0; r < 4; ++r) psum[r] += __shfl_xor(psum[r], m, 64);
    }
    if (c == 0) {
        const int rowbase = m0 + wave * 16 + q * 4;
#pragma unroll
        for (int r = 0; r < 4; ++r) atomicAdd(&scores[rowbase + r], psum[r]);
    }
}

// ---- softmax over S per batch -> alphas ----
__global__ __launch_bounds__(256) void softmax_k(const float* __restrict__ scores,
                                                 float* __restrict__ alphas) {
    __shared__ float red[256];
    const int b = blockIdx.x;
    const int tid = threadIdx.x;
    float loc[8];
    float mx = -1e30f;
#pragma unroll
    for (int i = 0; i < 8; ++i) {
        loc[i] = scores[b * SEQ + tid + i * 256];
        mx = fmaxf(mx, loc[i]);
    }
    red[tid] = mx; __syncthreads();
    for (int s = 128; s > 0; s >>= 1) {
        if (tid < s) red[tid] = fmaxf(red[tid], red[tid + s]);
        __syncthreads();
    }
    mx = red[0]; __syncthreads();
    float sum = 0.f;
#pragma unroll
    for (int i = 0; i < 8; ++i) { loc[i] = expf(loc[i] - mx); sum += loc[i]; }
    red[tid] = sum; __syncthreads();
    for (int s = 128; s > 0; s >>= 1) {
        if (tid < s) red[tid] += red[tid + s];
        __syncthreads();
    }
    const float inv = 1.0f / red[0];
#pragma unroll
    for (int i = 0; i < 8; ++i) alphas[b * SEQ + tid + i * 256] = loc[i] * inv;
}

// ---- context[b][h] = sum_s alphas[b][s] * values[b][s][h]  (s split 32-way, atomics) ----
__global__ __launch_bounds__(256) void context_k(const float* __restrict__ alphas,
                                                 const float* __restrict__ values,
                                                 float* __restrict__ context) {
    const int b = blockIdx.y;
    const int s0 = blockIdx.x * 64;
    const int col = threadIdx.x * 4;
    float4 acc = {0.f, 0.f, 0.f, 0.f};
    for (int i = 0; i < 64; ++i) {
        const int s = s0 + i;
        const float a = alphas[b * SEQ + s];
        const float4 v = *(const float4*)(values + (size_t)(b * SEQ + s) * HID + col);
        acc.x += a * v.x; acc.y += a * v.y; acc.z += a * v.z; acc.w += a * v.w;
    }
    float* c = context + b * HID + col;
    atomicAdd(c + 0, acc.x);
    atomicAdd(c + 1, acc.y);
    atomicAdd(c + 2, acc.z);
    atomicAdd(c + 3, acc.w);
}

extern "C" void kernel_launch(void* const* d_in, const int* in_sizes, int n_in,
                              void* d_out, int out_size, void* d_ws, size_t ws_size,
                              hipStream_t stream) {
    const float* queries = (const float*)d_in[0];
    const float* keys    = (const float*)d_in[1];
    const float* values  = (const float*)d_in[2];
    const float* W1      = (const float*)d_in[3];
    const float* b1      = (const float*)d_in[4];
    const float* W2      = (const float*)d_in[5];
    // d_in[6] = b2: softmax is shift-invariant, b2 does not affect alphas or context.

    float* out_ctx   = (float*)d_out;            // [16,1024]
    float* out_alpha = (float*)d_out + NB * HID; // [16,2048]

    char* ws = (char*)d_ws;
    float* scores = (float*)ws;                  // 32768 f32 = 131072 B
    float* qproj  = (float*)(ws + 131072);       // 16384 f32 = 65536 B
    short* w1t    = (short*)(ws + 196608);       // 1M bf16  = 2 MiB

    hipMemsetAsync(ws, 0, 196608, stream);                       // scores + qproj
    hipMemsetAsync(out_ctx, 0, NB * HID * sizeof(float), stream);

    prep_w1t  <<<dim3(32, 32),    256, 0, stream>>>(W1, w1t);
    prep_qproj<<<dim3(4, 4, NB),  256, 0, stream>>>(queries, W1, b1, qproj);
    score_gemm<<<dim3(16, 512),   256, 0, stream>>>(keys, w1t, qproj, W2, scores);
    softmax_k <<<NB,              256, 0, stream>>>(scores, out_alpha);
    context_k <<<dim3(32, NB),    256, 0, stream>>>(out_alpha, values, out_ctx);
}

// Round 2
// 443.410 us; speedup vs baseline: 1.2456x; 1.2456x over previous
//
#include <hip/hip_runtime.h>

#define HID 1024
#define SEQ 2048
#define NB  16

typedef __attribute__((ext_vector_type(8))) short bf16x8;
typedef __attribute__((ext_vector_type(4))) float f32x4;

static __device__ __forceinline__ short f2bf(float f) {
    union { float f; unsigned u; } v; v.f = f;
    unsigned u = v.u + 0x7fffu + ((v.u >> 16) & 1u);   // round-to-nearest-even
    return (short)(u >> 16);
}
static __device__ __forceinline__ unsigned pk2(float a, float b) {
    return (unsigned)(unsigned short)f2bf(a) | ((unsigned)(unsigned short)f2bf(b) << 16);
}
// async global->LDS, 16B per lane. LDS dest = wave-uniform base + lane*16.
static __device__ __forceinline__ void glds16(const void* g, void* l) {
    __builtin_amdgcn_global_load_lds(
        (const __attribute__((address_space(1))) unsigned*)g,
        (__attribute__((address_space(3))) unsigned*)l, 16, 0, 0);
}

// ---- fused prep: [0,nconv) keys->bf16 | [nconv,+1024) w1t transpose |
//                  [+64) qproj | [+32) zero scores ----
__global__ __launch_bounds__(256) void prep_all(const float* __restrict__ keys,
                                                short* __restrict__ kbf,
                                                const float* __restrict__ W1,
                                                const float* __restrict__ queries,
                                                const float* __restrict__ b1,
                                                short* __restrict__ w1t,
                                                float* __restrict__ qproj,
                                                float* __restrict__ scores,
                                                int nconv) {
    __shared__ float t[32][33];
    const int tid = threadIdx.x;
    int bw = blockIdx.x;
    if (bw < nconv) {  // keys fp32 -> bf16, 8 elems/thread
        const size_t i = ((size_t)bw * 256 + tid) * 8;
        const float4 a = *(const float4*)(keys + i);
        const float4 b = *(const float4*)(keys + i + 4);
        int4 o;
        o.x = (int)pk2(a.x, a.y); o.y = (int)pk2(a.z, a.w);
        o.z = (int)pk2(b.x, b.y); o.w = (int)pk2(b.z, b.w);
        *(int4*)(kbf + i) = o;
        return;
    }
    bw -= nconv;
    if (bw < 1024) {  // w1t[n][k] = bf16(W1[H+k][n])
        const int k0 = (bw & 31) * 32;
        const int n0 = (bw >> 5) * 32;
        const int tx = tid & 31, ty = tid >> 5;
#pragma unroll
        for (int i = 0; i < 32; i += 8)
            t[ty + i][tx] = W1[(size_t)(HID + k0 + ty + i) * HID + n0 + tx];
        __syncthreads();
#pragma unroll
        for (int i = 0; i < 32; i += 8)
            w1t[(size_t)(n0 + ty + i) * HID + k0 + tx] = f2bf(t[tx][ty + i]);
        return;
    }
    bw -= 1024;
    if (bw < 64) {  // qproj[b][n] = b1[n] + q[b,:] @ W1_top[:,n]
        const int u = bw * 256 + tid;
        const int b = u >> 10, n = u & 1023;
        const float* q = queries + b * HID;
        float acc = b1[n];
#pragma unroll 8
        for (int f = 0; f < HID; ++f)
            acc += q[f] * W1[(size_t)f * HID + n];
        qproj[u] = acc;
        return;
    }
    bw -= 64;
    {  // zero scores (32 blocks x 256 x float4 = 32768 floats)
        float4 z = {0.f, 0.f, 0.f, 0.f};
        *(float4*)(scores + (size_t)(bw * 256 + tid) * 4) = z;
    }
}

// ---- main fused score GEMM: 128x128 tile, BK=32, 4 waves (2x2), 4x4 frags/wave.
// scores[m] += sum_n relu(keys[m]·W1bot[:,n] + qproj[b][n]) * W2[n]
template<int PRE>
__global__ __launch_bounds__(256) void score_gemm128(const float* __restrict__ keys,
                                                     const short* __restrict__ kbf,
                                                     const short* __restrict__ w1t,
                                                     const float* __restrict__ qproj,
                                                     const float* __restrict__ W2,
                                                     float* __restrict__ scores) {
    __shared__ short As[128 * 32];  // [m][k] bf16, unpadded (glds layout)
    __shared__ short Bs[128 * 32];  // [n][k] bf16, unpadded

    const int tid  = threadIdx.x;
    const int lane = tid & 63;
    const int wave = tid >> 6;
    const int n0 = blockIdx.x * 128;
    const int m0 = blockIdx.y * 128;
    const int batch = m0 >> 11;
    const int wm = wave >> 1, wn = wave & 1;   // wave quadrant
    const int q = lane >> 4, c = lane & 15;

    // glds per-call lane mapping: row = callrow + lane/4, k-chunk = (lane&3)*8
    const int lrow = lane >> 2;
    const int lk   = (lane & 3) * 8;

    f32x4 acc[4][4] = {};

    for (int k0 = 0; k0 < HID; k0 += 32) {
        // B: 8 KB via 2 glds calls per wave
#pragma unroll
        for (int call = 0; call < 2; ++call) {
            const int rbase = (wave * 2 + call) * 16;
            glds16(w1t + (size_t)(n0 + rbase + lrow) * HID + k0 + lk,
                   &Bs[rbase * 32]);
        }
        if (PRE) {
            // A: 8 KB via 2 glds calls per wave from pre-converted bf16 keys
#pragma unroll
            for (int call = 0; call < 2; ++call) {
                const int rbase = (wave * 2 + call) * 16;
                glds16(kbf + (size_t)(m0 + rbase + lrow) * HID + k0 + lk,
                       &As[rbase * 32]);
            }
        } else {
            // A: convert fp32->bf16 in-register. thread t: row t>>1, half t&1 (16 floats)
            const int r = tid >> 1, h = (tid & 1) * 16;
            const float* src = keys + (size_t)(m0 + r) * HID + k0 + h;
            const float4 v0 = *(const float4*)(src + 0);
            const float4 v1 = *(const float4*)(src + 4);
            const float4 v2 = *(const float4*)(src + 8);
            const float4 v3 = *(const float4*)(src + 12);
            int4 o0, o1;
            o0.x = (int)pk2(v0.x, v0.y); o0.y = (int)pk2(v0.z, v0.w);
            o0.z = (int)pk2(v1.x, v1.y); o0.w = (int)pk2(v1.z, v1.w);
            o1.x = (int)pk2(v2.x, v2.y); o1.y = (int)pk2(v2.z, v2.w);
            o1.z = (int)pk2(v3.x, v3.y); o1.w = (int)pk2(v3.z, v3.w);
            *(int4*)&As[r * 32 + h + 0] = o0;
            *(int4*)&As[r * 32 + h + 8] = o1;
        }
        __syncthreads();

        bf16x8 af[4], bf[4];
#pragma unroll
        for (int i = 0; i < 4; ++i)
            af[i] = *(const bf16x8*)&As[(wm * 64 + i * 16 + c) * 32 + q * 8];
#pragma unroll
        for (int i = 0; i < 4; ++i)
            bf[i] = *(const bf16x8*)&Bs[(wn * 64 + i * 16 + c) * 32 + q * 8];
#pragma unroll
        for (int mi = 0; mi < 4; ++mi)
#pragma unroll
            for (int ni = 0; ni < 4; ++ni)
                acc[mi][ni] = __builtin_amdgcn_mfma_f32_16x16x32_bf16(af[mi], bf[ni], acc[mi][ni], 0, 0, 0);
        __syncthreads();
    }

    // epilogue: relu(acc + qproj) * W2, reduce over this wave's 64 n-cols
    const float* qp = qproj + batch * HID + n0 + wn * 64;
    const float* w2 = W2 + n0 + wn * 64;
    float psum[4][4] = {};
#pragma unroll
    for (int ni = 0; ni < 4; ++ni) {
        const float qv = qp[ni * 16 + c];
        const float wv = w2[ni * 16 + c];
#pragma unroll
        for (int mi = 0; mi < 4; ++mi)
#pragma unroll
            for (int r = 0; r < 4; ++r)
                psum[mi][r] += fmaxf(acc[mi][ni][r] + qv, 0.f) * wv;
    }
#pragma unroll
    for (int m = 1; m < 16; m <<= 1)
#pragma unroll
        for (int mi = 0; mi < 4; ++mi)
#pragma unroll
            for (int r = 0; r < 4; ++r)
                psum[mi][r] += __shfl_xor(psum[mi][r], m, 64);
    if (c == 0) {
#pragma unroll
        for (int mi = 0; mi < 4; ++mi) {
            const int row = m0 + wm * 64 + mi * 16 + q * 4;
#pragma unroll
            for (int r = 0; r < 4; ++r)
                atomicAdd(&scores[row + r], psum[mi][r]);
        }
    }
}

// ---- softmax over S per batch -> alphas; also zero context accumulator ----
__global__ __launch_bounds__(256) void softmax_k(const float* __restrict__ scores,
                                                 float* __restrict__ alphas,
                                                 float* __restrict__ ctx) {
    __shared__ float red[256];
    const int b = blockIdx.x;
    const int tid = threadIdx.x;
    float4 z = {0.f, 0.f, 0.f, 0.f};
    *(float4*)(ctx + b * HID + tid * 4) = z;

    float loc[8];
    float mx = -1e30f;
#pragma unroll
    for (int i = 0; i < 8; ++i) {
        loc[i] = scores[b * SEQ + tid + i * 256];
        mx = fmaxf(mx, loc[i]);
    }
    red[tid] = mx; __syncthreads();
    for (int s = 128; s > 0; s >>= 1) {
        if (tid < s) red[tid] = fmaxf(red[tid], red[tid + s]);
        __syncthreads();
    }
    mx = red[0]; __syncthreads();
    float sum = 0.f;
#pragma unroll
    for (int i = 0; i < 8; ++i) { loc[i] = expf(loc[i] - mx); sum += loc[i]; }
    red[tid] = sum; __syncthreads();
    for (int s = 128; s > 0; s >>= 1) {
        if (tid < s) red[tid] += red[tid + s];
        __syncthreads();
    }
    const float inv = 1.0f / red[0];
#pragma unroll
    for (int i = 0; i < 8; ++i) alphas[b * SEQ + tid + i * 256] = loc[i] * inv;
}

// ---- context[b][h] = sum_s alphas[b][s] * values[b][s][h] (s split 32-way, atomics) ----
__global__ __launch_bounds__(256) void context_k(const float* __restrict__ alphas,
                                                 const float* __restrict__ values,
                                                 float* __restrict__ context) {
    const int b = blockIdx.y;
    const int s0 = blockIdx.x * 64;
    const int col = threadIdx.x * 4;
    float4 acc = {0.f, 0.f, 0.f, 0.f};
    for (int i = 0; i < 64; ++i) {
        const int s = s0 + i;
        const float a = alphas[b * SEQ + s];
        const float4 v = *(const float4*)(values + (size_t)(b * SEQ + s) * HID + col);
        acc.x += a * v.x; acc.y += a * v.y; acc.z += a * v.z; acc.w += a * v.w;
    }
    float* cp = context + b * HID + col;
    atomicAdd(cp + 0, acc.x);
    atomicAdd(cp + 1, acc.y);
    atomicAdd(cp + 2, acc.z);
    atomicAdd(cp + 3, acc.w);
}

extern "C" void kernel_launch(void* const* d_in, const int* in_sizes, int n_in,
                              void* d_out, int out_size, void* d_ws, size_t ws_size,
                              hipStream_t stream) {
    const float* queries = (const float*)d_in[0];
    const float* keys    = (const float*)d_in[1];
    const float* values  = (const float*)d_in[2];
    const float* W1      = (const float*)d_in[3];
    const float* b1      = (const float*)d_in[4];
    const float* W2      = (const float*)d_in[5];
    // d_in[6] = b2: softmax is shift-invariant; b2 affects neither alphas nor context.

    float* out_ctx   = (float*)d_out;            // [16,1024]
    float* out_alpha = (float*)d_out + NB * HID; // [16,2048]

    char* ws = (char*)d_ws;
    float* scores = (float*)ws;                       // 131072 B
    float* qproj  = (float*)(ws + 131072);            // 65536 B
    short* w1t    = (short*)(ws + 196608);            // 2 MiB
    short* kbf    = (short*)(ws + 2293760);           // 64 MiB (preconv path)

    const size_t need_pre = 2293760ull + 67108864ull;
    const bool pre = ws_size >= need_pre;
    const int nconv = pre ? 16384 : 0;   // 33.5M elems / 2048 per block

    prep_all<<<nconv + 1024 + 64 + 32, 256, 0, stream>>>(
        keys, kbf, W1, queries, b1, w1t, qproj, scores, nconv);

    if (pre)
        score_gemm128<1><<<dim3(8, 256), 256, 0, stream>>>(keys, kbf, w1t, qproj, W2, scores);
    else
        score_gemm128<0><<<dim3(8, 256), 256, 0, stream>>>(keys, kbf, w1t, qproj, W2, scores);

    softmax_k<<<NB, 256, 0, stream>>>(scores, out_alpha, out_ctx);
    context_k<<<dim3(32, NB), 256, 0, stream>>>(out_alpha, values, out_ctx);
}

// Round 3
// 383.030 us; speedup vs baseline: 1.4419x; 1.1576x over previous
//
#include <hip/hip_runtime.h>

#define HID 1024
#define SEQ 2048
#define NB  16

typedef __attribute__((ext_vector_type(8))) short bf16x8;
typedef __attribute__((ext_vector_type(4))) float f32x4;

static __device__ __forceinline__ short f2bf(float f) {
    union { float f; unsigned u; } v; v.f = f;
    unsigned u = v.u + 0x7fffu + ((v.u >> 16) & 1u);   // round-to-nearest-even
    return (short)(u >> 16);
}
static __device__ __forceinline__ unsigned pk2(float a, float b) {
    return (unsigned)(unsigned short)f2bf(a) | ((unsigned)(unsigned short)f2bf(b) << 16);
}
// async global->LDS, 16B per lane. LDS dest = wave-uniform base + lane*16.
static __device__ __forceinline__ void glds16(const void* g, void* l) {
    __builtin_amdgcn_global_load_lds(
        (const __attribute__((address_space(1))) unsigned*)g,
        (__attribute__((address_space(3))) unsigned*)l, 16, 0, 0);
}

// ---- fused prep. Block order chosen so the small latency-bound sections
// launch FIRST and overlap the BW-bound keys conversion:
//   [0,32)          qproj (atomic, f-split 8 x n-split 4, 16 batch-accs/thread)
//   [32,1056)       w1t transpose
//   [1056,1056+nconv) keys fp32->bf16
__global__ __launch_bounds__(256) void prep_all(const float* __restrict__ keys,
                                                short* __restrict__ kbf,
                                                const float* __restrict__ W1,
                                                const float* __restrict__ queries,
                                                const float* __restrict__ b1,
                                                short* __restrict__ w1t,
                                                float* __restrict__ qproj,
                                                int nconv) {
    __shared__ float shmem[2048];          // 8 KB, aliased per section
    const int tid = threadIdx.x;
    int bw = blockIdx.x;

    if (bw < 32) {  // qproj[b][n] += b1 + sum_f q[b][f]*W1[f][n], f-chunk 128, n-chunk 256
        const int f0 = (bw >> 2) * 128;
        const int n0 = (bw & 3) * 256;
        // stage q[0:16][f0:f0+128] into LDS (2048 floats)
#pragma unroll
        for (int j = 0; j < 8; ++j) {
            const int idx = tid * 8 + j;
            const int b = idx >> 7, f = idx & 127;
            shmem[idx] = queries[b * HID + f0 + f];
        }
        __syncthreads();
        float acc[16];
        const float bv = (bw >> 2 == 0) ? b1[n0 + tid] : 0.0f;
#pragma unroll
        for (int b = 0; b < 16; ++b) acc[b] = (b == 0) ? bv : 0.0f;
        if (bw >> 2 == 0) {
#pragma unroll
            for (int b = 1; b < 16; ++b) acc[b] = bv;
        }
        for (int f = 0; f < 128; ++f) {
            const float w = W1[(size_t)(f0 + f) * HID + n0 + tid];
#pragma unroll
            for (int b = 0; b < 16; ++b)
                acc[b] += shmem[b * 128 + f] * w;
        }
        // b1 must be added exactly once per (b,n): only the f0==0 chunk seeds it,
        // but the loop above seeded all 16 accs — correct since each (b,n) cell is
        // touched by exactly one f0==0 block.
#pragma unroll
        for (int b = 0; b < 16; ++b)
            atomicAdd(&qproj[b * HID + n0 + tid], acc[b]);
        return;
    }
    bw -= 32;
    if (bw < 1024) {  // w1t[n][k] = bf16(W1[H+k][n])
        float (*t)[33] = (float(*)[33])shmem;   // 32x33 floats
        const int k0 = (bw & 31) * 32;
        const int n0 = (bw >> 5) * 32;
        const int tx = tid & 31, ty = tid >> 5;
#pragma unroll
        for (int i = 0; i < 32; i += 8)
            t[ty + i][tx] = W1[(size_t)(HID + k0 + ty + i) * HID + n0 + tx];
        __syncthreads();
#pragma unroll
        for (int i = 0; i < 32; i += 8)
            w1t[(size_t)(n0 + ty + i) * HID + k0 + tx] = f2bf(t[tx][ty + i]);
        return;
    }
    bw -= 1024;
    if (bw < nconv) {  // keys fp32 -> bf16, 8 elems/thread
        const size_t i = ((size_t)bw * 256 + tid) * 8;
        const float4 a = *(const float4*)(keys + i);
        const float4 b = *(const float4*)(keys + i + 4);
        int4 o;
        o.x = (int)pk2(a.x, a.y); o.y = (int)pk2(a.z, a.w);
        o.z = (int)pk2(b.x, b.y); o.w = (int)pk2(b.z, b.w);
        *(int4*)(kbf + i) = o;
    }
}

// ---- main fused score GEMM: 128x128 tile, BK=32, 4 waves (2x2), 4x4 frags/wave.
// scores[m] += sum_n relu(keys[m]·W1bot[:,n] + qproj[b][n]) * W2[n]
template<int PRE>
__global__ __launch_bounds__(256) void score_gemm128(const float* __restrict__ keys,
                                                     const short* __restrict__ kbf,
                                                     const short* __restrict__ w1t,
                                                     const float* __restrict__ qproj,
                                                     const float* __restrict__ W2,
                                                     float* __restrict__ scores) {
    __shared__ short As[128 * 32];  // [m][k] bf16, unpadded (glds layout)
    __shared__ short Bs[128 * 32];  // [n][k] bf16, unpadded

    const int tid  = threadIdx.x;
    const int lane = tid & 63;
    const int wave = tid >> 6;
    const int n0 = blockIdx.x * 128;
    const int m0 = blockIdx.y * 128;
    const int batch = m0 >> 11;
    const int wm = wave >> 1, wn = wave & 1;   // wave quadrant
    const int q = lane >> 4, c = lane & 15;

    // glds per-call lane mapping: row = callrow + lane/4, k-chunk = (lane&3)*8
    const int lrow = lane >> 2;
    const int lk   = (lane & 3) * 8;

    f32x4 acc[4][4] = {};

    for (int k0 = 0; k0 < HID; k0 += 32) {
        // B: 8 KB via 2 glds calls per wave
#pragma unroll
        for (int call = 0; call < 2; ++call) {
            const int rbase = (wave * 2 + call) * 16;
            glds16(w1t + (size_t)(n0 + rbase + lrow) * HID + k0 + lk,
                   &Bs[rbase * 32]);
        }
        if (PRE) {
            // A: 8 KB via 2 glds calls per wave from pre-converted bf16 keys
#pragma unroll
            for (int call = 0; call < 2; ++call) {
                const int rbase = (wave * 2 + call) * 16;
                glds16(kbf + (size_t)(m0 + rbase + lrow) * HID + k0 + lk,
                       &As[rbase * 32]);
            }
        } else {
            // A: convert fp32->bf16 in-register. thread t: row t>>1, half t&1 (16 floats)
            const int r = tid >> 1, h = (tid & 1) * 16;
            const float* src = keys + (size_t)(m0 + r) * HID + k0 + h;
            const float4 v0 = *(const float4*)(src + 0);
            const float4 v1 = *(const float4*)(src + 4);
            const float4 v2 = *(const float4*)(src + 8);
            const float4 v3 = *(const float4*)(src + 12);
            int4 o0, o1;
            o0.x = (int)pk2(v0.x, v0.y); o0.y = (int)pk2(v0.z, v0.w);
            o0.z = (int)pk2(v1.x, v1.y); o0.w = (int)pk2(v1.z, v1.w);
            o1.x = (int)pk2(v2.x, v2.y); o1.y = (int)pk2(v2.z, v2.w);
            o1.z = (int)pk2(v3.x, v3.y); o1.w = (int)pk2(v3.z, v3.w);
            *(int4*)&As[r * 32 + h + 0] = o0;
            *(int4*)&As[r * 32 + h + 8] = o1;
        }
        __syncthreads();

        bf16x8 af[4], bf[4];
#pragma unroll
        for (int i = 0; i < 4; ++i)
            af[i] = *(const bf16x8*)&As[(wm * 64 + i * 16 + c) * 32 + q * 8];
#pragma unroll
        for (int i = 0; i < 4; ++i)
            bf[i] = *(const bf16x8*)&Bs[(wn * 64 + i * 16 + c) * 32 + q * 8];
#pragma unroll
        for (int mi = 0; mi < 4; ++mi)
#pragma unroll
            for (int ni = 0; ni < 4; ++ni)
                acc[mi][ni] = __builtin_amdgcn_mfma_f32_16x16x32_bf16(af[mi], bf[ni], acc[mi][ni], 0, 0, 0);
        __syncthreads();
    }

    // epilogue: relu(acc + qproj) * W2, reduce over this wave's 64 n-cols
    const float* qp = qproj + batch * HID + n0 + wn * 64;
    const float* w2 = W2 + n0 + wn * 64;
    float psum[4][4] = {};
#pragma unroll
    for (int ni = 0; ni < 4; ++ni) {
        const float qv = qp[ni * 16 + c];
        const float wv = w2[ni * 16 + c];
#pragma unroll
        for (int mi = 0; mi < 4; ++mi)
#pragma unroll
            for (int r = 0; r < 4; ++r)
                psum[mi][r] += fmaxf(acc[mi][ni][r] + qv, 0.f) * wv;
    }
#pragma unroll
    for (int m = 1; m < 16; m <<= 1)
#pragma unroll
        for (int mi = 0; mi < 4; ++mi)
#pragma unroll
            for (int r = 0; r < 4; ++r)
                psum[mi][r] += __shfl_xor(psum[mi][r], m, 64);
    if (c == 0) {
#pragma unroll
        for (int mi = 0; mi < 4; ++mi) {
            const int row = m0 + wm * 64 + mi * 16 + q * 4;
#pragma unroll
            for (int r = 0; r < 4; ++r)
                atomicAdd(&scores[row + r], psum[mi][r]);
        }
    }
}

// ---- softmax over S per batch -> alphas; also zero context accumulator ----
__global__ __launch_bounds__(256) void softmax_k(const float* __restrict__ scores,
                                                 float* __restrict__ alphas,
                                                 float* __restrict__ ctx) {
    __shared__ float red[256];
    const int b = blockIdx.x;
    const int tid = threadIdx.x;
    float4 z = {0.f, 0.f, 0.f, 0.f};
    *(float4*)(ctx + b * HID + tid * 4) = z;

    float loc[8];
    float mx = -1e30f;
#pragma unroll
    for (int i = 0; i < 8; ++i) {
        loc[i] = scores[b * SEQ + tid + i * 256];
        mx = fmaxf(mx, loc[i]);
    }
    red[tid] = mx; __syncthreads();
    for (int s = 128; s > 0; s >>= 1) {
        if (tid < s) red[tid] = fmaxf(red[tid], red[tid + s]);
        __syncthreads();
    }
    mx = red[0]; __syncthreads();
    float sum = 0.f;
#pragma unroll
    for (int i = 0; i < 8; ++i) { loc[i] = expf(loc[i] - mx); sum += loc[i]; }
    red[tid] = sum; __syncthreads();
    for (int s = 128; s > 0; s >>= 1) {
        if (tid < s) red[tid] += red[tid + s];
        __syncthreads();
    }
    const float inv = 1.0f / red[0];
#pragma unroll
    for (int i = 0; i < 8; ++i) alphas[b * SEQ + tid + i * 256] = loc[i] * inv;
}

// ---- context[b][h] = sum_s alphas[b][s] * values[b][s][h] (s split 32-way, atomics) ----
__global__ __launch_bounds__(256) void context_k(const float* __restrict__ alphas,
                                                 const float* __restrict__ values,
                                                 float* __restrict__ context) {
    const int b = blockIdx.y;
    const int s0 = blockIdx.x * 64;
    const int col = threadIdx.x * 4;
    float4 acc = {0.f, 0.f, 0.f, 0.f};
    for (int i = 0; i < 64; ++i) {
        const int s = s0 + i;
        const float a = alphas[b * SEQ + s];
        const float4 v = *(const float4*)(values + (size_t)(b * SEQ + s) * HID + col);
        acc.x += a * v.x; acc.y += a * v.y; acc.z += a * v.z; acc.w += a * v.w;
    }
    float* cp = context + b * HID + col;
    atomicAdd(cp + 0, acc.x);
    atomicAdd(cp + 1, acc.y);
    atomicAdd(cp + 2, acc.z);
    atomicAdd(cp + 3, acc.w);
}

extern "C" void kernel_launch(void* const* d_in, const int* in_sizes, int n_in,
                              void* d_out, int out_size, void* d_ws, size_t ws_size,
                              hipStream_t stream) {
    const float* queries = (const float*)d_in[0];
    const float* keys    = (const float*)d_in[1];
    const float* values  = (const float*)d_in[2];
    const float* W1      = (const float*)d_in[3];
    const float* b1      = (const float*)d_in[4];
    const float* W2      = (const float*)d_in[5];
    // d_in[6] = b2: softmax is shift-invariant; b2 affects neither alphas nor context.

    float* out_ctx   = (float*)d_out;            // [16,1024]
    float* out_alpha = (float*)d_out + NB * HID; // [16,2048]

    char* ws = (char*)d_ws;
    float* scores = (float*)ws;                       // 131072 B
    float* qproj  = (float*)(ws + 131072);            // 65536 B
    short* w1t    = (short*)(ws + 196608);            // 2 MiB
    short* kbf    = (short*)(ws + 2293760);           // 64 MiB (preconv path)

    const size_t need_pre = 2293760ull + 67108864ull;
    const bool pre = ws_size >= need_pre;
    const int nconv = pre ? 16384 : 0;   // 33.5M elems / 2048 per block

    hipMemsetAsync(ws, 0, 196608, stream);   // scores + qproj (atomic targets)

    prep_all<<<32 + 1024 + nconv, 256, 0, stream>>>(
        keys, kbf, W1, queries, b1, w1t, qproj, nconv);

    if (pre)
        score_gemm128<1><<<dim3(8, 256), 256, 0, stream>>>(keys, kbf, w1t, qproj, W2, scores);
    else
        score_gemm128<0><<<dim3(8, 256), 256, 0, stream>>>(keys, kbf, w1t, qproj, W2, scores);

    softmax_k<<<NB, 256, 0, stream>>>(scores, out_alpha, out_ctx);
    context_k<<<dim3(32, NB), 256, 0, stream>>>(out_alpha, values, out_ctx);
}